// Round 3
// baseline (479.882 us; speedup 1.0000x reference)
//
#include <hip/hip_runtime.h>
#include <stdint.h>
#include <stddef.h>

#define NN 8192      // nodes
#define KD 256       // in_dim
#define CD 256       // out_dim*heads
#define FD 128       // out_dim
#define BI 32        // i-tile rows per block (k_gat)
#define BJ 32        // j-tile (k_gat)

typedef __attribute__((ext_vector_type(4))) float f32x4;
typedef __attribute__((ext_vector_type(8))) short b16x8;

__device__ __forceinline__ unsigned short f2bf(float x) {
    unsigned int u = __float_as_uint(x);
    u += 0x7fffu + ((u >> 16) & 1u);
    return (unsigned short)(u >> 16);
}

// async global->LDS, 16B per lane; lds dest = wave-uniform base + lane*16
__device__ __forceinline__ void async16(const void* g, void* l) {
    __builtin_amdgcn_global_load_lds(
        (const __attribute__((address_space(1))) unsigned int*)g,
        (__attribute__((address_space(3))) unsigned int*)l, 16, 0, 0);
}

// masked exp(leaky(sv+d)) for 8 j's -> bf16 pack into w LDS; returns sum
__device__ __forceinline__ float exp_pack_store(
    const int4 a0, const int4 a1, const float4 d0, const float4 d1,
    float sv, unsigned short* wdst)
{
    const int am[8] = {a0.x, a0.y, a0.z, a0.w, a1.x, a1.y, a1.z, a1.w};
    const float dd[8] = {d0.x, d0.y, d0.z, d0.w, d1.x, d1.y, d1.z, d1.w};
    const float ninf = __int_as_float(0xff800000);
    float e[8]; float dp = 0.f;
#pragma unroll
    for (int k = 0; k < 8; ++k) {
        float x = sv + dd[k];
        x = fmaxf(x, 0.f) + 0.2f * fminf(x, 0.f);   // leaky_relu(0.2)
        x = am[k] != 0 ? x : ninf;                   // mask: exp(-inf)=0
        const float ev = __expf(x);
        dp += ev; e[k] = ev;
    }
    union { unsigned short us[8]; b16x8 v; } pk;
#if __has_builtin(__builtin_amdgcn_cvt_pk_bf16_f32)
#pragma unroll
    for (int k = 0; k < 4; ++k) {
        auto p = __builtin_amdgcn_cvt_pk_bf16_f32(e[2 * k], e[2 * k + 1]);
        __builtin_memcpy(&pk.us[2 * k], &p, 4);
    }
#else
#pragma unroll
    for (int k = 0; k < 8; ++k) pk.us[k] = f2bf(e[k]);
#endif
    *(b16x8*)wdst = pk.v;
    return dp;
}

// ---------------------------------------------------------------------------
// Kernel 1: T = feat @ W.T (bf16 MFMA) fused with scores (transposed layout)
// and transposed bf16 output Tt[c][n].  grid=128, block=256
// ---------------------------------------------------------------------------
__global__ __launch_bounds__(256) void k_transform(
    const float* __restrict__ feat, const float* __restrict__ W,
    const float* __restrict__ asrc, const float* __restrict__ adst,
    unsigned short* __restrict__ Tt, float* __restrict__ s_t, float* __restrict__ d_t)
{
    __shared__ unsigned short a_lds[64 * 32];    // 4KB
    __shared__ unsigned short b_lds[256 * 32];   // 16KB
    __shared__ unsigned short tr_lds[256 * 72];  // 36KB
    __shared__ float sc_lds[4][64];              // 1KB
    __shared__ float dc_lds[4][64];              // 1KB

    const int t = threadIdx.x;
    const int wave = t >> 6, lane = t & 63;
    const int l15 = lane & 15, quad = lane >> 4;
    const int n0 = blockIdx.x * 64;
    const int ai = t >> 2, ag = t & 3;

    f32x4 acc[4][4] = {};
    for (int kc = 0; kc < 8; ++kc) {
        const int k0 = kc * 32;
        __syncthreads();
        { // stage A: features[n0+ai][k0 + ag*8 .. +7] -> bf16
            const float* src = feat + (size_t)(n0 + ai) * KD + k0 + ag * 8;
            const float4 v0 = *(const float4*)src;
            const float4 v1 = *(const float4*)(src + 4);
            union { unsigned short us[8]; b16x8 v; } pk;
            pk.us[0] = f2bf(v0.x); pk.us[1] = f2bf(v0.y);
            pk.us[2] = f2bf(v0.z); pk.us[3] = f2bf(v0.w);
            pk.us[4] = f2bf(v1.x); pk.us[5] = f2bf(v1.y);
            pk.us[6] = f2bf(v1.z); pk.us[7] = f2bf(v1.w);
            const int slot = ag ^ ((ai >> 1) & 3);
            *(b16x8*)&a_lds[ai * 32 + slot * 8] = pk.v;
        }
        for (int p = 0; p < 4; ++p) { // stage B: W[c][k0 + g*8 .. +7]
            const int G = p * 256 + t;
            const int c = G >> 2, g = G & 3;
            const float* src = W + (size_t)c * KD + k0 + g * 8;
            const float4 v0 = *(const float4*)src;
            const float4 v1 = *(const float4*)(src + 4);
            union { unsigned short us[8]; b16x8 v; } pk;
            pk.us[0] = f2bf(v0.x); pk.us[1] = f2bf(v0.y);
            pk.us[2] = f2bf(v0.z); pk.us[3] = f2bf(v0.w);
            pk.us[4] = f2bf(v1.x); pk.us[5] = f2bf(v1.y);
            pk.us[6] = f2bf(v1.z); pk.us[7] = f2bf(v1.w);
            const int slot = g ^ ((c >> 1) & 3);
            *(b16x8*)&b_lds[c * 32 + slot * 8] = pk.v;
        }
        __syncthreads();
        b16x8 af[4], bfr[4];
        for (int mt = 0; mt < 4; ++mt) {
            const int m = mt * 16 + l15;
            af[mt] = *(const b16x8*)&a_lds[m * 32 + (quad ^ ((m >> 1) & 3)) * 8];
        }
        for (int nt = 0; nt < 4; ++nt) {
            const int c = wave * 64 + nt * 16 + l15;
            bfr[nt] = *(const b16x8*)&b_lds[c * 32 + (quad ^ ((c >> 1) & 3)) * 8];
        }
        for (int mt = 0; mt < 4; ++mt)
            for (int nt = 0; nt < 4; ++nt)
                acc[mt][nt] = __builtin_amdgcn_mfma_f32_16x16x32_bf16(
                    af[mt], bfr[nt], acc[mt][nt], 0, 0, 0);
    }

    // ---- epilogue: scores (fp32) + transposed bf16 store ----
    float aS[4], aD[4];
    for (int nt = 0; nt < 4; ++nt) {
        const int c = wave * 64 + nt * 16 + l15;
        aS[nt] = asrc[c]; aD[nt] = adst[c];
    }
    for (int mt = 0; mt < 4; ++mt)
        for (int r = 0; r < 4; ++r) {
            float vs = 0.f, vd = 0.f;
            for (int nt = 0; nt < 4; ++nt) {
                const float x = acc[mt][nt][r];
                vs += x * aS[nt]; vd += x * aD[nt];
            }
            vs += __shfl_xor(vs, 1); vd += __shfl_xor(vd, 1);
            vs += __shfl_xor(vs, 2); vd += __shfl_xor(vd, 2);
            vs += __shfl_xor(vs, 4); vd += __shfl_xor(vd, 4);
            vs += __shfl_xor(vs, 8); vd += __shfl_xor(vd, 8);
            if (l15 == 0) {
                const int nl = mt * 16 + quad * 4 + r;
                sc_lds[wave][nl] = vs; dc_lds[wave][nl] = vd;
            }
        }
    for (int mt = 0; mt < 4; ++mt)
        for (int nt = 0; nt < 4; ++nt)
            for (int r = 0; r < 4; ++r) {
                const int c = wave * 64 + nt * 16 + l15;
                const int n = mt * 16 + quad * 4 + r;
                tr_lds[c * 72 + n] = f2bf(acc[mt][nt][r]);
            }
    __syncthreads();
    if (t < 128) {
        const int n = t >> 1, h = t & 1;
        s_t[(size_t)h * NN + n0 + n] = sc_lds[h * 2][n] + sc_lds[h * 2 + 1][n];
        d_t[(size_t)h * NN + n0 + n] = dc_lds[h * 2][n] + dc_lds[h * 2 + 1][n];
    }
    for (int p = 0; p < 8; ++p) {
        const int idx = p * 256 + t;       // 2048 granules
        const int c = idx >> 3, g = idx & 7;
        *(b16x8*)(Tt + (size_t)c * NN + n0 + g * 8) = *(const b16x8*)&tr_lds[c * 72 + g * 8];
    }
}

// ---------------------------------------------------------------------------
// Kernel 2: fused masked-softmax aggregation — single-barrier software
// pipeline. dbuf tt (async, 2x16KB) + dbuf w (2x4KB) = 40KB -> 4 blocks/CU.
// grid=(256, jsplit), block=256.
// ---------------------------------------------------------------------------
__global__ __launch_bounds__(256, 4) void k_gat(
    const int* __restrict__ adj, const unsigned short* __restrict__ Tt,
    const float* __restrict__ s_t, const float* __restrict__ d_t,
    float* __restrict__ num_part,   // [jsplit][NN][CD]
    float* __restrict__ den_part,   // [jsplit][2][NN]
    int njt)
{
    __shared__ unsigned short tt_lds[2][256 * 32];   // 32KB, dbuf, addr-perm swizzle
    __shared__ unsigned short w_lds[2][2][32][32];   // 8KB, dbuf

    const int t = threadIdx.x;
    const int wave = t >> 6, lane = t & 63;
    const int l15 = lane & 15, quad = lane >> 4;
    const int i0 = blockIdx.x * BI;
    const int chunk = blockIdx.y;
    const size_t jbase = (size_t)chunk * njt * BJ;

    // exp-side mapping: head / row / j-granule
    const int eh = t >> 7;
    const int wi = (t & 127) >> 2;
    const int g4 = t & 3;
    const int gi = i0 + wi;
    const float sv = s_t[(size_t)eh * NN + gi];
    const int wslot = (g4 ^ ((wi >> 1) & 3)) * 8;

    // mfma-side mapping: head / f-half per wave
    const int mh = wave >> 1, fh = wave & 1;
    const int cbase = mh * 128 + fh * 64;

    f32x4 acc[2][4] = {};
    float den = 0.f;

    const int* ap = adj + (size_t)gi * NN + jbase + g4 * 8;
    const float* dp_ = d_t + (size_t)eh * NN + jbase + g4 * 8;

    // ---- prologue: tile0 asyncs + tile0/1 adj,d + exp[0] -> w[0] ----
    for (int p = 0; p < 4; ++p) {
        const int G = (p * 4 + wave) * 64 + lane;
        const int c = G >> 2;
        const int g = (G & 3) ^ ((c >> 1) & 3);
        async16(Tt + (size_t)c * NN + jbase + g * 8,
                (char*)&tt_lds[0][0] + (size_t)(p * 4 + wave) * 1024);
    }
    __builtin_amdgcn_sched_barrier(0);
    int4 cA0 = ((const int4*)ap)[0], cA1 = ((const int4*)ap)[1];
    float4 cD0 = ((const float4*)dp_)[0], cD1 = ((const float4*)dp_)[1];
    {
        const int j1 = (njt > 1) ? BJ : 0;
        int4 nA0 = *(const int4*)(ap + j1);
        int4 nA1 = *(const int4*)(ap + j1 + 4);
        float4 nD0 = *(const float4*)(dp_ + j1);
        float4 nD1 = *(const float4*)(dp_ + j1 + 4);
        den += exp_pack_store(cA0, cA1, cD0, cD1, sv, &w_lds[0][eh][wi][wslot]);
        cA0 = nA0; cA1 = nA1; cD0 = nD0; cD1 = nD1;
    }
    // drain tile0 asyncs (+older reg loads); make w[0] visible
    asm volatile("s_waitcnt vmcnt(4) lgkmcnt(0)\n\ts_barrier" ::: "memory");

    // ---- main loop: ONE barrier per iteration ----
    for (int jt = 0; jt < njt; ++jt) {
        const int cur = jt & 1, nxt = cur ^ 1;
        // 1. fragment ds_reads from [cur]
        b16x8 af[2], bfr[4];
        for (int mt = 0; mt < 2; ++mt) {
            const int m = mt * 16 + l15;
            af[mt] = *(const b16x8*)&w_lds[cur][mh][m][(quad ^ ((m >> 1) & 3)) * 8];
        }
        for (int nt = 0; nt < 4; ++nt) {
            const int c = cbase + nt * 16 + l15;
            bfr[nt] = *(const b16x8*)&tt_lds[cur][c * 32 + (quad ^ ((c >> 1) & 3)) * 8];
        }
        // 2. async Tt tile jt+1 (clamped) -> [nxt]   (4 issues/wave, oldest in FIFO)
        const size_t jnext = jbase + (size_t)((jt + 1 < njt) ? jt + 1 : jt) * BJ;
        for (int p = 0; p < 4; ++p) {
            const int G = (p * 4 + wave) * 64 + lane;
            const int c = G >> 2;
            const int g = (G & 3) ^ ((c >> 1) & 3);
            async16(Tt + (size_t)c * NN + jnext + g * 8,
                    (char*)&tt_lds[nxt][0] + (size_t)(p * 4 + wave) * 1024);
        }
        __builtin_amdgcn_sched_barrier(0);   // pin FIFO: asyncs before reg loads
        // 3. adj/d prefetch, 2 tiles ahead (clamped) — 4 loads, stay in flight
        const int j2 = (((jt + 2 < njt) ? jt + 2 : njt - 1)) * BJ;
        int4 nA0 = *(const int4*)(ap + j2);
        int4 nA1 = *(const int4*)(ap + j2 + 4);
        float4 nD0 = *(const float4*)(dp_ + j2);
        float4 nD1 = *(const float4*)(dp_ + j2 + 4);
        // 4. exp for tile jt+1 -> w_lds[nxt] (overlaps this iter's asyncs)
        const float dpv = exp_pack_store(cA0, cA1, cD0, cD1, sv,
                                         &w_lds[nxt][eh][wi][wslot]);
        if (jt + 1 < njt) den += dpv;        // skip clamped tail duplicate
        // 5. MFMA tile jt
        for (int mt = 0; mt < 2; ++mt)
            for (int nt = 0; nt < 4; ++nt)
                acc[mt][nt] = __builtin_amdgcn_mfma_f32_16x16x32_bf16(
                    af[mt], bfr[nt], acc[mt][nt], 0, 0, 0);
        // 6. rotate; barrier drains ONLY this iter's asyncs (vmcnt 4 = keep
        //    the 4 newest adj/d prefetch loads in flight)
        cA0 = nA0; cA1 = nA1; cD0 = nD0; cD1 = nD1;
        asm volatile("s_waitcnt vmcnt(4) lgkmcnt(0)\n\ts_barrier" ::: "memory");
    }

    // den reduce over g4 lanes (lane bits 0..1)
    float dv = den;
    dv += __shfl_xor(dv, 1); dv += __shfl_xor(dv, 2);
    if (g4 == 0)
        den_part[((size_t)chunk * 2 + eh) * NN + gi] = dv;

    float* np_ = num_part + (size_t)chunk * NN * CD;
    for (int mt = 0; mt < 2; ++mt)
        for (int nt = 0; nt < 4; ++nt)
            for (int r = 0; r < 4; ++r) {
                const int n = i0 + mt * 16 + quad * 4 + r;
                const int c = cbase + nt * 16 + l15;
                np_[(size_t)n * CD + c] = acc[mt][nt][r];
            }
}

// ---------------------------------------------------------------------------
// Kernel 3: combine partials, normalize, mean over heads.  grid=4096
// ---------------------------------------------------------------------------
__global__ __launch_bounds__(256) void k_combine(
    const float* __restrict__ num_part, const float* __restrict__ den_part,
    float* __restrict__ out, int jsplit)
{
    const int idx = blockIdx.x * 256 + threadIdx.x;   // NN*FD
    const int n = idx >> 7, f = idx & 127;
    const size_t row = (size_t)n * CD;
    float n0 = 0.f, n1 = 0.f, d0 = 0.f, d1 = 0.f;
    for (int c = 0; c < jsplit; ++c) {
        const size_t base = (size_t)c * NN * CD;
        n0 += num_part[base + row + f];
        n1 += num_part[base + row + 128 + f];
        d0 += den_part[((size_t)c * 2 + 0) * NN + n];
        d1 += den_part[((size_t)c * 2 + 1) * NN + n];
    }
    const float r0 = d0 != 0.f ? n0 / d0 : 0.f;
    const float r1 = d1 != 0.f ? n1 / d1 : 0.f;
    out[idx] = 0.5f * (r0 + r1);
}

// ---------------------------------------------------------------------------
extern "C" void kernel_launch(void* const* d_in, const int* in_sizes, int n_in,
                              void* d_out, int out_size, void* d_ws, size_t ws_size,
                              hipStream_t stream) {
    const float* feat = (const float*)d_in[0];
    const int*   adj  = (const int*)d_in[1];
    const float* W    = (const float*)d_in[2];
    const float* asrc = (const float*)d_in[3];
    const float* adst = (const float*)d_in[4];
    float* out = (float*)d_out;

    const int jsplit = (ws_size >= ((size_t)40 << 20)) ? 4 : 2;
    const int njt = (NN / jsplit) / BJ;

    char* ws = (char*)d_ws;
    unsigned short* Tt = (unsigned short*)ws;                       // 4 MB
    float* s_t  = (float*)(ws + ((size_t)4 << 20));                 // 64 KB
    float* d_t  = (float*)(ws + ((size_t)4 << 20) + (64 << 10));    // 64 KB
    float* den  = (float*)(ws + ((size_t)4 << 20) + (128 << 10));   // <=256 KB
    float* nump = (float*)(ws + ((size_t)8 << 20));                 // jsplit*8 MB

    k_transform<<<128, 256, 0, stream>>>(feat, W, asrc, adst, Tt, s_t, d_t);
    k_gat<<<dim3(NN / BI, jsplit), 256, 0, stream>>>(adj, Tt, s_t, d_t, nump, den, njt);
    k_combine<<<NN * FD / 256, 256, 0, stream>>>(nump, den, out, jsplit);
}